// Round 1
// baseline (123.992 us; speedup 1.0000x reference)
//
#include <hip/hip_runtime.h>

// Problem constants (from reference setup_inputs)
constexpr int NPTS = 8192;   // points per batch
constexpr int NQ   = 2048;   // query points per batch
constexpr int NC   = 64;     // feature channels
constexpr int NS   = 32;     // nsample
constexpr int QPB  = 8;      // queries per block (one wave each)
constexpr int NCH  = 3 + 1 + NC;           // 68 output channels
constexpr int CS   = NQ * NS;              // channel stride in output (floats)

// inv semi-axes^2 for radius=0.2: [25, 6.25, 25]
// density: exp(-dist^2 / 0.02) / 0.25 ; output channel 3 = 1/density

__global__ __launch_bounds__(512, 2) void ellip_query_group_kernel(
    const float* __restrict__ xyz,    // (B, NPTS, 3)
    const float* __restrict__ nxyz,   // (B, NQ, 3)
    const float* __restrict__ feat,   // (B, NC, NPTS)
    float* __restrict__ out)          // (B, NCH, NQ, NS)
{
    __shared__ int idx_s[QPB][NS];

    const int b    = blockIdx.y;
    const int p0   = blockIdx.x * QPB;
    const int tid  = threadIdx.x;
    const int lane = tid & 63;
    const int wave = tid >> 6;   // 0..7 : query within block

    const float* xb = xyz + (size_t)b * NPTS * 3;

    // ---------------- phase 1: ballot-scan ellipsoid query, 1 wave/query ---
    {
        const int p = p0 + wave;
        const float qx = nxyz[((size_t)b * NQ + p) * 3 + 0];
        const float qy = nxyz[((size_t)b * NQ + p) * 3 + 1];
        const float qz = nxyz[((size_t)b * NQ + p) * 3 + 2];

        int cnt = 0;      // wave-uniform hit count
        int first = -1;   // wave-uniform first-hit index

        for (int base = 0; base < NPTS; base += 64) {
            const int i = base + lane;
            const float x = xb[i * 3 + 0];
            const float y = xb[i * 3 + 1];
            const float z = xb[i * 3 + 2];
            // strict per-op rounding, reference evaluation order:
            // q = ((dx*dx)*25 + (dy*dy)*6.25) + (dz*dz)*25
            const float dx = __fsub_rn(qx, x);
            const float dy = __fsub_rn(qy, y);
            const float dz = __fsub_rn(qz, z);
            const float t0 = __fmul_rn(__fmul_rn(dx, dx), 25.0f);
            const float t1 = __fmul_rn(__fmul_rn(dy, dy), 6.25f);
            const float t2 = __fmul_rn(__fmul_rn(dz, dz), 25.0f);
            const float qv = __fadd_rn(__fadd_rn(t0, t1), t2);
            const bool hit = qv < 1.0f;

            const unsigned long long m = __ballot(hit);
            if (first < 0 && m != 0ull)
                first = base + __builtin_ctzll(m);   // wave-uniform
            if (hit) {
                const int pos = cnt + __popcll(m & ((1ull << lane) - 1ull));
                if (pos < NS) idx_s[wave][pos] = i;
            }
            cnt += __popcll(m);
            if (cnt >= NS) break;   // uniform branch: early exit
        }
        if (cnt < NS) {
            const int f = (cnt == 0) ? 0 : first;   // pad with first hit (0 if none)
            if (lane < NS && lane >= cnt) idx_s[wave][lane] = f;
        }
    }
    __syncthreads();

    // ---------------- phase 2: gather + density + coalesced write ----------
    // 512 threads = 8 queries x 32 samples x 2 channel-parity halves
    const int s = tid & 31;
    const int h = (tid >> 5) & 1;
    const int q = tid >> 6;
    const int p = p0 + q;
    const int j = idx_s[q][s];

    const float qx = nxyz[((size_t)b * NQ + p) * 3 + 0];
    const float qy = nxyz[((size_t)b * NQ + p) * 3 + 1];
    const float qz = nxyz[((size_t)b * NQ + p) * 3 + 2];
    const float px = xb[j * 3 + 0];
    const float py = xb[j * 3 + 1];
    const float pz = xb[j * 3 + 2];

    // dist^2 in reference order: (dx^2 + dy^2) + dz^2, strict rounding
    const float dx = __fsub_rn(px, qx);
    const float dy = __fsub_rn(py, qy);
    const float dz = __fsub_rn(pz, qz);
    const float d2 = __fadd_rn(__fadd_rn(__fmul_rn(dx, dx), __fmul_rn(dy, dy)),
                               __fmul_rn(dz, dz));
    const float dist = __fsqrt_rn(d2);
    // density = exp(-dist^2 / 0.02) / 0.25 ; channel = 1/density
    const float arg  = __fdiv_rn(-__fmul_rn(dist, dist), 0.02f);
    const float density = __fmul_rn(expf(arg), 4.0f);   // /0.25 == *4 (exact)
    const float gd = __fdiv_rn(1.0f, density);          // inf on underflow, matches ref

    float* ob = out + ((size_t)b * NCH * NQ + p) * NS + s;

    if (h == 0) {
        ob[0 * (size_t)CS] = px;
        ob[2 * (size_t)CS] = pz;
    } else {
        ob[1 * (size_t)CS] = py;
        ob[3 * (size_t)CS] = gd;
    }

    // features: channel-parity split, coalesced 1KB stores per channel
    const float* fb = feat + (size_t)b * NC * NPTS + j;
    #pragma unroll 4
    for (int c = h; c < NC; c += 2) {
        ob[(size_t)(4 + c) * CS] = fb[(size_t)c * NPTS];
    }
}

extern "C" void kernel_launch(void* const* d_in, const int* in_sizes, int n_in,
                              void* d_out, int out_size, void* d_ws, size_t ws_size,
                              hipStream_t stream) {
    const float* xyz  = (const float*)d_in[0];   // (B, 8192, 3)
    const float* nxyz = (const float*)d_in[1];   // (B, 2048, 3)
    const float* feat = (const float*)d_in[2];   // (B, 64, 8192)
    float* out = (float*)d_out;                  // (B, 68, 2048, 32)

    const int B = in_sizes[0] / (NPTS * 3);

    dim3 grid(NQ / QPB, B);
    dim3 block(512);
    ellip_query_group_kernel<<<grid, block, 0, stream>>>(xyz, nxyz, feat, out);
}

// Round 2
// 113.323 us; speedup vs baseline: 1.0941x; 1.0941x over previous
//
#include <hip/hip_runtime.h>

// Problem constants (from reference setup_inputs)
constexpr int NPTS = 8192;   // points per batch
constexpr int NQ   = 2048;   // query points per batch
constexpr int NC   = 64;     // feature channels
constexpr int NS   = 32;     // nsample
constexpr int QPB  = 8;      // queries per block (one wave each)
constexpr int NCH  = 3 + 1 + NC;           // 68 output channels
constexpr int CS   = NQ * NS;              // channel stride in output (floats)

// ---------------------------------------------------------------------------
// Kernel 0: tiled transpose features (B,C,N) -> (B,N,C) into workspace.
// 64x64 tiles via padded LDS; both global sides fully coalesced (256B/inst).
// ---------------------------------------------------------------------------
__global__ __launch_bounds__(256, 8) void transpose_feat_kernel(
    const float* __restrict__ feat,   // (B, NC, NPTS)
    float* __restrict__ ftr)          // (B, NPTS, NC)
{
    __shared__ float tile[NC][65];    // +1 pad: LDS reads (c + p) % 32 -> 2-way, free

    const int b  = blockIdx.y;
    const int n0 = blockIdx.x * 64;
    const int t  = threadIdx.x;

    const float* fb = feat + (size_t)b * NC * NPTS;
    {
        const int pl = t & 63;
        const int c0 = t >> 6;        // 0..3
        #pragma unroll
        for (int i = 0; i < 16; ++i) {
            const int c = c0 + 4 * i;
            tile[c][pl] = fb[(size_t)c * NPTS + n0 + pl];
        }
    }
    __syncthreads();
    float* tb = ftr + ((size_t)b * NPTS + n0) * NC;
    {
        const int cl = t & 63;
        const int pb = t >> 6;        // 0..3
        #pragma unroll
        for (int i = 0; i < 16; ++i) {
            const int pp = pb + 4 * i;
            tb[(size_t)pp * NC + cl] = tile[cl][pp];
        }
    }
}

// ---------------------------------------------------------------------------
// Phase-1 helper: ballot-scan ellipsoid query, one wave per query.
// Writes NS ascending hit indices (padded with first hit / 0) into idx_s.
// Strict per-op rounding in the reference's evaluation order: the q<1.0
// compare is discontinuous, so no FMA contraction allowed here.
// ---------------------------------------------------------------------------
__device__ __forceinline__ void ellipsoid_scan(
    const float* __restrict__ xb, const float* __restrict__ nxyz,
    int b, int p, int lane, int* __restrict__ idx_row)
{
    const float qx = nxyz[((size_t)b * NQ + p) * 3 + 0];
    const float qy = nxyz[((size_t)b * NQ + p) * 3 + 1];
    const float qz = nxyz[((size_t)b * NQ + p) * 3 + 2];

    int cnt = 0;      // wave-uniform hit count
    int first = -1;   // wave-uniform first-hit index

    for (int base = 0; base < NPTS; base += 64) {
        const int i = base + lane;
        const float x = xb[i * 3 + 0];
        const float y = xb[i * 3 + 1];
        const float z = xb[i * 3 + 2];
        const float dx = __fsub_rn(qx, x);
        const float dy = __fsub_rn(qy, y);
        const float dz = __fsub_rn(qz, z);
        const float t0 = __fmul_rn(__fmul_rn(dx, dx), 25.0f);
        const float t1 = __fmul_rn(__fmul_rn(dy, dy), 6.25f);
        const float t2 = __fmul_rn(__fmul_rn(dz, dz), 25.0f);
        const float qv = __fadd_rn(__fadd_rn(t0, t1), t2);
        const bool hit = qv < 1.0f;

        const unsigned long long m = __ballot(hit);
        if (first < 0 && m != 0ull)
            first = base + __builtin_ctzll(m);   // wave-uniform
        if (hit) {
            const int pos = cnt + __popcll(m & ((1ull << lane) - 1ull));
            if (pos < NS) idx_row[pos] = i;
        }
        cnt += __popcll(m);
        if (cnt >= NS) break;   // uniform branch: early exit
    }
    if (cnt < NS) {
        const int f = (cnt == 0) ? 0 : first;    // pad with first hit (0 if none)
        if (lane < NS && lane >= cnt) idx_row[lane] = f;
    }
}

// ---------------------------------------------------------------------------
// Phase-2 helper: xyz + inverse-density channels (threads r<32 of each wave).
// ---------------------------------------------------------------------------
__device__ __forceinline__ void write_xyz_density(
    const float* __restrict__ xb, const float* __restrict__ nxyz,
    int b, int p, int j, float* __restrict__ ob)
{
    const float qx = nxyz[((size_t)b * NQ + p) * 3 + 0];
    const float qy = nxyz[((size_t)b * NQ + p) * 3 + 1];
    const float qz = nxyz[((size_t)b * NQ + p) * 3 + 2];
    const float px = xb[j * 3 + 0];
    const float py = xb[j * 3 + 1];
    const float pz = xb[j * 3 + 2];

    const float dx = __fsub_rn(px, qx);
    const float dy = __fsub_rn(py, qy);
    const float dz = __fsub_rn(pz, qz);
    const float d2 = __fadd_rn(__fadd_rn(__fmul_rn(dx, dx), __fmul_rn(dy, dy)),
                               __fmul_rn(dz, dz));
    const float dist = __fsqrt_rn(d2);
    const float arg  = __fdiv_rn(-__fmul_rn(dist, dist), 0.02f);
    const float density = __fmul_rn(expf(arg), 4.0f);   // /0.25 == *4 (exact)
    const float gd = __fdiv_rn(1.0f, density);          // inf on underflow == ref

    ob[0 * (size_t)CS] = px;
    ob[1 * (size_t)CS] = py;
    ob[2 * (size_t)CS] = pz;
    ob[3 * (size_t)CS] = gd;
}

// ---------------------------------------------------------------------------
// Main kernel (transposed-features path): float4 contiguous gathers.
// 512 threads = 8 waves; wave q owns query p0+q for both phases.
// ---------------------------------------------------------------------------
__global__ __launch_bounds__(512, 8) void ellip_main_t_kernel(
    const float* __restrict__ xyz,    // (B, NPTS, 3)
    const float* __restrict__ nxyz,   // (B, NQ, 3)
    const float* __restrict__ ftr,    // (B, NPTS, NC) transposed
    float* __restrict__ out)          // (B, NCH, NQ, NS)
{
    __shared__ int idx_s[QPB][NS];

    const int b    = blockIdx.y;
    const int p0   = blockIdx.x * QPB;
    const int tid  = threadIdx.x;
    const int lane = tid & 63;
    const int wave = tid >> 6;

    const float* xb = xyz + (size_t)b * NPTS * 3;

    ellipsoid_scan(xb, nxyz, b, p0 + wave, lane, idx_s[wave]);
    __syncthreads();

    // phase 2: wave q -> query p0+q; lane r -> sample s=r&31, cg parity r>>5
    const int q = tid >> 6;
    const int r = tid & 63;
    const int p = p0 + q;
    const int s = r & 31;
    const int j = idx_s[q][s];

    float* ob = out + ((size_t)b * NCH * NQ + p) * NS + s;

    if (r < 32)
        write_xyz_density(xb, nxyz, b, p, j, ob);

    // features: 16 float4 groups per point; parity split across half-waves.
    // All 8 loads per thread are independent -> pipelined; each wave inst
    // touches 32 distinct 32B chunks (vs 64 scattered 4B lines before).
    const float4* fp = (const float4*)(ftr + ((size_t)b * NPTS + j) * NC);
    const int cg0 = r >> 5;   // 0 or 1
    #pragma unroll
    for (int k = 0; k < 8; ++k) {
        const int cg = cg0 + 2 * k;
        const float4 v = fp[cg];
        float* oc = ob + (size_t)(4 + 4 * cg) * CS;
        oc[0 * (size_t)CS] = v.x;
        oc[1 * (size_t)CS] = v.y;
        oc[2 * (size_t)CS] = v.z;
        oc[3 * (size_t)CS] = v.w;
    }
}

// ---------------------------------------------------------------------------
// Fallback (no workspace): direct strided gather from (B,C,N) features.
// ---------------------------------------------------------------------------
__global__ __launch_bounds__(512, 8) void ellip_main_direct_kernel(
    const float* __restrict__ xyz,
    const float* __restrict__ nxyz,
    const float* __restrict__ feat,   // (B, NC, NPTS)
    float* __restrict__ out)
{
    __shared__ int idx_s[QPB][NS];

    const int b    = blockIdx.y;
    const int p0   = blockIdx.x * QPB;
    const int tid  = threadIdx.x;
    const int lane = tid & 63;
    const int wave = tid >> 6;

    const float* xb = xyz + (size_t)b * NPTS * 3;

    ellipsoid_scan(xb, nxyz, b, p0 + wave, lane, idx_s[wave]);
    __syncthreads();

    const int s = tid & 31;
    const int h = (tid >> 5) & 1;
    const int q = tid >> 6;
    const int p = p0 + q;
    const int j = idx_s[q][s];

    float* ob = out + ((size_t)b * NCH * NQ + p) * NS + s;

    if (h == 0)
        write_xyz_density(xb, nxyz, b, p, j, ob);

    const float* fb = feat + (size_t)b * NC * NPTS + j;
    #pragma unroll 4
    for (int c = h; c < NC; c += 2)
        ob[(size_t)(4 + c) * CS] = fb[(size_t)c * NPTS];
}

extern "C" void kernel_launch(void* const* d_in, const int* in_sizes, int n_in,
                              void* d_out, int out_size, void* d_ws, size_t ws_size,
                              hipStream_t stream) {
    const float* xyz  = (const float*)d_in[0];   // (B, 8192, 3)
    const float* nxyz = (const float*)d_in[1];   // (B, 2048, 3)
    const float* feat = (const float*)d_in[2];   // (B, 64, 8192)
    float* out = (float*)d_out;                  // (B, 68, 2048, 32)

    const int B = in_sizes[0] / (NPTS * 3);
    const size_t trans_bytes = (size_t)B * NPTS * NC * sizeof(float);

    if (ws_size >= trans_bytes) {
        float* ftr = (float*)d_ws;
        transpose_feat_kernel<<<dim3(NPTS / 64, B), 256, 0, stream>>>(feat, ftr);
        ellip_main_t_kernel<<<dim3(NQ / QPB, B), 512, 0, stream>>>(xyz, nxyz, ftr, out);
    } else {
        ellip_main_direct_kernel<<<dim3(NQ / QPB, B), 512, 0, stream>>>(xyz, nxyz, feat, out);
    }
}